// Round 1
// 2063.822 us; speedup vs baseline: 6.2575x; 6.2575x over previous
//
#include <hip/hip_runtime.h>
#include <hip/hip_fp16.h>

// BilinearAttention: context = softmax(mask? -1e9 : Q@K) @ V
// B=16, Tq=Tk=2048, D=1024, fp32 in/out.
// Round 2: MFMA flash attention.
//   QK^T : bf16 hi/lo split (3x mfma_f32_16x16x32_bf16) -> fp32 scores, err ~5e-4
//   P@V  : fp16 (P in [0,1] fp16 as in prior verified kernel; V fp16)
//   WG = 512 thr (8 waves), BQ=64 q-rows, BT=256 kv-tile.
//   QK: wave w owns S cols [w*32,+32); Q staged in LDS (bf16 hi/lo, XOR-swizzled),
//       K loaded direct global->B-fragments (coalesced 64B lines, 1x per WG).
//   PV: wave w owns O cols [w*128,+128); V staged transposed fp16 [d][t] rows
//       padded to 80B; P staged fp16 swizzled. O accum = 32 C-frags = 128 VGPR.
//   Softmax: in-register, DPP row_ror reduce over 16 lanes + 8-wave LDS reduce.
//   XCD-grouped block swizzle: XCD x processes batches {2x, 2x+1}.

#define B_    16
#define TQ    2048
#define TK    2048
#define DH    1024
#define BQ    64
#define BT    256
#define DC    128
#define NTHR  512
#define NEG_INF_ -1.0e9f

typedef __attribute__((ext_vector_type(8))) short     bf16x8;
typedef __attribute__((ext_vector_type(4))) short     s16x4;
typedef __attribute__((ext_vector_type(8))) _Float16  f16x8;
typedef __attribute__((ext_vector_type(4))) _Float16  f16x4;
typedef __attribute__((ext_vector_type(4))) float     f32x4;

// ---------------- mask dtype detection (verified in prior round) ---------
// flag: 0 = int32, 1 = float32, 2 = uint8 bytes.
__global__ void detect_mask_kernel(const void* __restrict__ mask, int* flag_out) {
    const int tid = threadIdx.x;
    const int*   mi = (const int*)mask;
    const float* mf = (const float*)mask;
    int ok_i = 1, ok_f = 1;
    for (int k = 0; k < 16; ++k) {
        int idx = tid * 16 + k;
        int iv = mi[idx];
        ok_i &= ((iv == 0) | (iv == 1));
        float fv = mf[idx];
        ok_f &= ((fv == 0.0f) | (fv == 1.0f));
    }
    int all_i = __syncthreads_and(ok_i);
    int all_f = __syncthreads_and(ok_f);
    if (tid == 0) flag_out[0] = all_i ? 0 : (all_f ? 1 : 2);
}

// ---------------- DPP 16-lane row reduce (VALU-rate, no DS) --------------
template<int CTRL>
__device__ __forceinline__ float dpp_rot(float x) {
    return __int_as_float(__builtin_amdgcn_update_dpp(
        0, __float_as_int(x), CTRL, 0xf, 0xf, false));
}
__device__ __forceinline__ float rowmax16(float v) {
    v = fmaxf(v, dpp_rot<0x128>(v));   // row_ror:8
    v = fmaxf(v, dpp_rot<0x124>(v));   // row_ror:4
    v = fmaxf(v, dpp_rot<0x122>(v));   // row_ror:2
    v = fmaxf(v, dpp_rot<0x121>(v));   // row_ror:1
    return v;
}
__device__ __forceinline__ float rowsum16(float v) {
    v += dpp_rot<0x128>(v);
    v += dpp_rot<0x124>(v);
    v += dpp_rot<0x122>(v);
    v += dpp_rot<0x121>(v);
    return v;
}

// load K rows [D0+g*8, +8) at cols tcol, tcol+16 -> two raw f32[8]
#define LOADK(D0, R0, R1) do {                                              \
    const float* kp_ = Kb + (size_t)((D0) + g * 8) * TK + tcol;             \
    _Pragma("unroll")                                                       \
    for (int j_ = 0; j_ < 8; ++j_) {                                        \
        (R0)[j_] = kp_[(size_t)j_ * TK];                                    \
        (R1)[j_] = kp_[(size_t)j_ * TK + 16];                               \
    }                                                                       \
} while (0)

// split f32[8] -> bf16 hi / bf16 lo fragments (truncation split)
#define PACKBF(SRC, H, L) do {                                              \
    _Pragma("unroll")                                                       \
    for (int j_ = 0; j_ < 8; ++j_) {                                        \
        float x_ = (SRC)[j_];                                               \
        unsigned xb_ = __float_as_uint(x_);                                 \
        (H)[j_] = (short)(xb_ >> 16);                                       \
        float lo_ = x_ - __uint_as_float(xb_ & 0xffff0000u);                \
        (L)[j_] = (short)(__float_as_uint(lo_) >> 16);                      \
    }                                                                       \
} while (0)

__global__ __launch_bounds__(NTHR, 2)
void flash_attn_kernel(const float* __restrict__ Q, const float* __restrict__ K,
                       const float* __restrict__ V, const void* __restrict__ Mask,
                       const int* __restrict__ flagp, float* __restrict__ Out) {
    __shared__ union {
        struct { unsigned short qh[BQ * DC];          // 16 KB bf16-hi, swizzled
                 unsigned short ql[BQ * DC]; } qk;    // 16 KB bf16-lo
        unsigned short vst[DH * 40];                  // 80 KB V^T fp16, 80B rows
    } smu;
    __shared__ unsigned short pbuf[BQ * BT];          // 32 KB P fp16, swizzled
    __shared__ float red [BQ][9];
    __shared__ float red2[BQ][9];
    __shared__ float m_s[BQ], l_s[BQ], alpha_s[BQ];

    const int tid  = threadIdx.x;
    const int w    = tid >> 6;     // wave 0..7
    const int ln   = tid & 63;
    const int g    = ln >> 4;      // 0..3 k-group / C-row-group
    const int lx   = ln & 15;      // 0..15 A-row / B-col / C-col
    const int flag = flagp[0];

    // XCD-grouped remap (dispatch i -> XCD i%8): XCD x gets batches {2x,2x+1}
    const int lin = blockIdx.y * gridDim.x + blockIdx.x;
    const int nl  = (lin & 7) * 64 + (lin >> 3);
    const int b   = nl >> 5;
    const int q0  = (nl & 31) * BQ;

    const float* Qb = Q + ((size_t)b * TQ + q0) * DH;
    const float* Kb = K + (size_t)b * DH * TK;
    const float* Vb = V + (size_t)b * TK * DH;

    const f32x4 zero4 = {0.f, 0.f, 0.f, 0.f};
    f32x4 acc[4][8];               // O: rows mt*16+g*4+r, cols w*128+nt*16+lx
#pragma unroll
    for (int mt = 0; mt < 4; ++mt)
#pragma unroll
        for (int nt = 0; nt < 8; ++nt) acc[mt][nt] = zero4;

    if (tid < BQ) { m_s[tid] = -3.0e38f; l_s[tid] = 0.0f; }
    __syncthreads();

#pragma unroll 1
    for (int t0 = 0; t0 < TK; t0 += BT) {
        // ============ QK^T : S[64][256], wave w -> cols [w*32,+32) ========
        const int tcol = t0 + w * 32 + lx;
        f32x4 sacc[4][2];
#pragma unroll
        for (int mt = 0; mt < 4; ++mt) { sacc[mt][0] = zero4; sacc[mt][1] = zero4; }

        float kr0[2][8], kr1[2][8];
#pragma unroll 1
        for (int c = 0; c < DH / DC; ++c) {
            const int dc = c * DC;
            LOADK(dc, kr0[0], kr1[0]);          // prefetch ks=0 (flies over staging)
            __syncthreads();                    // LDS region reuse guard
            // ---- stage Q[64][dc..dc+128) -> bf16 hi/lo, XOR-swizzled ----
            {
                const int q    = tid >> 3;
                const int dgb  = (tid & 7) * 16;
                const float* qrow = Qb + (size_t)q * DH + dc;
                const int sw   = (q & 7) << 4;
                const int rowb = q * (DC * 2);
#pragma unroll
                for (int i = 0; i < 4; ++i) {
                    const int d = dgb + i * 4;
                    const float4 qv = *(const float4*)(qrow + d);
                    const float* qf = reinterpret_cast<const float*>(&qv);
                    s16x4 h4, l4;
#pragma unroll
                    for (int e = 0; e < 4; ++e) {
                        unsigned xb = __float_as_uint(qf[e]);
                        h4[e] = (short)(xb >> 16);
                        float lo = qf[e] - __uint_as_float(xb & 0xffff0000u);
                        l4[e] = (short)(__float_as_uint(lo) >> 16);
                    }
                    const int off = rowb + ((d * 2) ^ sw);
                    *(s16x4*)((char*)smu.qk.qh + off) = h4;
                    *(s16x4*)((char*)smu.qk.ql + off) = l4;
                }
            }
            __syncthreads();
#pragma unroll
            for (int ks = 0; ks < 4; ++ks) {
                if (ks < 3) LOADK(dc + (ks + 1) * 32, kr0[(ks + 1) & 1], kr1[(ks + 1) & 1]);
                bf16x8 kh0, kl0, kh1, kl1;
                PACKBF(kr0[ks & 1], kh0, kl0);
                PACKBF(kr1[ks & 1], kh1, kl1);
                const int kloc = (ks * 32 + g * 8) * 2;
#pragma unroll
                for (int mt = 0; mt < 4; ++mt) {
                    const int row = mt * 16 + lx;
                    const int off = row * (DC * 2) + (kloc ^ ((row & 7) << 4));
                    const bf16x8 aqh = *(const bf16x8*)((const char*)smu.qk.qh + off);
                    const bf16x8 aql = *(const bf16x8*)((const char*)smu.qk.ql + off);
                    // S = Qh*Kh + Ql*Kh + Qh*Kl  (drop Ql*Kl, ~2^-16)
                    sacc[mt][0] = __builtin_amdgcn_mfma_f32_16x16x32_bf16(aqh, kh0, sacc[mt][0], 0, 0, 0);
                    sacc[mt][0] = __builtin_amdgcn_mfma_f32_16x16x32_bf16(aql, kh0, sacc[mt][0], 0, 0, 0);
                    sacc[mt][0] = __builtin_amdgcn_mfma_f32_16x16x32_bf16(aqh, kl0, sacc[mt][0], 0, 0, 0);
                    sacc[mt][1] = __builtin_amdgcn_mfma_f32_16x16x32_bf16(aqh, kh1, sacc[mt][1], 0, 0, 0);
                    sacc[mt][1] = __builtin_amdgcn_mfma_f32_16x16x32_bf16(aql, kh1, sacc[mt][1], 0, 0, 0);
                    sacc[mt][1] = __builtin_amdgcn_mfma_f32_16x16x32_bf16(aqh, kl1, sacc[mt][1], 0, 0, 0);
                }
            }
        }

        // ============ mask + online softmax (in-register) =================
        float rmx[4][4];
#pragma unroll
        for (int mt = 0; mt < 4; ++mt)
#pragma unroll
        for (int r = 0; r < 4; ++r) {
            const int row = mt * 16 + g * 4 + r;
            const size_t mrow = ((size_t)(b * TQ + q0 + row)) * TK + tcol;
            bool mk0, mk1;
            if (flag == 0) {
                const int* Mi = (const int*)Mask;
                mk0 = Mi[mrow] != 0;        mk1 = Mi[mrow + 16] != 0;
            } else if (flag == 1) {
                const float* Mf = (const float*)Mask;
                mk0 = Mf[mrow] != 0.0f;     mk1 = Mf[mrow + 16] != 0.0f;
            } else {
                const unsigned char* Mu = (const unsigned char*)Mask;
                mk0 = Mu[mrow] != 0;        mk1 = Mu[mrow + 16] != 0;
            }
            if (mk0) sacc[mt][0][r] = NEG_INF_;
            if (mk1) sacc[mt][1][r] = NEG_INF_;
            rmx[mt][r] = rowmax16(fmaxf(sacc[mt][0][r], sacc[mt][1][r]));
        }
        if (lx == 0) {
#pragma unroll
            for (int mt = 0; mt < 4; ++mt)
#pragma unroll
            for (int r = 0; r < 4; ++r)
                red[mt * 16 + g * 4 + r][w] = rmx[mt][r];
        }
        __syncthreads();
        if (tid < BQ) {
            float m8 = red[tid][0];
#pragma unroll
            for (int k = 1; k < 8; ++k) m8 = fmaxf(m8, red[tid][k]);
            const float mo = m_s[tid];
            const float mn = fmaxf(mo, m8);
            m_s[tid]     = mn;
            alpha_s[tid] = __expf(mo - mn);   // exp(-3e38-mn) -> 0 on first tile
        }
        __syncthreads();
        // P = exp(S - m) -> fp16 LDS (swizzled), per-row partial sums
#pragma unroll
        for (int mt = 0; mt < 4; ++mt)
#pragma unroll
        for (int r = 0; r < 4; ++r) {
            const int row = mt * 16 + g * 4 + r;
            const float mn = m_s[row];
            const float p0 = __expf(sacc[mt][0][r] - mn);
            const float p1 = __expf(sacc[mt][1][r] - mn);
            const int rb = row * (BT * 2);
            const int sw = (row & 7) << 4;
            const _Float16 h0 = (_Float16)p0, h1 = (_Float16)p1;
            *(_Float16*)((char*)pbuf + rb + (((w * 32 + lx) * 2) ^ sw))      = h0;
            *(_Float16*)((char*)pbuf + rb + (((w * 32 + 16 + lx) * 2) ^ sw)) = h1;
            const float rs = rowsum16(p0 + p1);
            if (lx == 0) red2[row][w] = rs;
        }
        __syncthreads();
        if (tid < BQ) {
            float s8 = red2[tid][0];
#pragma unroll
            for (int k = 1; k < 8; ++k) s8 += red2[tid][k];
            l_s[tid] = l_s[tid] * alpha_s[tid] + s8;
        }
        // ---- rescale O by alpha (LDS broadcast reads) ----
#pragma unroll
        for (int mt = 0; mt < 4; ++mt)
#pragma unroll
        for (int r = 0; r < 4; ++r) {
            const float a = alpha_s[mt * 16 + g * 4 + r];
#pragma unroll
            for (int nt = 0; nt < 8; ++nt) acc[mt][nt][r] *= a;
        }

        // ============ P@V : wave w -> O cols [w*128,+128) =================
#pragma unroll 1
        for (int tc = 0; tc < BT / 32; ++tc) {
            __syncthreads();   // vst reuse guard (also first-tc vs qk region)
            // stage V^T[d][tloc] fp16 for t in [t0+tc*32, +32), rows 80 B
            {
                const int tb4 = (tid & 7) * 4;
                const int db  = tid >> 3;
                const float* Vc = Vb + (size_t)(t0 + tc * 32 + tb4) * DH;
#pragma unroll
                for (int it = 0; it < 4; ++it) {
                    const int d4 = db * 4 + it * 256;
                    const float4 v0 = *(const float4*)(Vc + 0 * DH + d4);
                    const float4 v1 = *(const float4*)(Vc + 1 * DH + d4);
                    const float4 v2 = *(const float4*)(Vc + 2 * DH + d4);
                    const float4 v3 = *(const float4*)(Vc + 3 * DH + d4);
                    const float* f0 = reinterpret_cast<const float*>(&v0);
                    const float* f1 = reinterpret_cast<const float*>(&v1);
                    const float* f2 = reinterpret_cast<const float*>(&v2);
                    const float* f3 = reinterpret_cast<const float*>(&v3);
#pragma unroll
                    for (int i = 0; i < 4; ++i) {
                        f16x4 hv;
                        hv[0] = (_Float16)f0[i];
                        hv[1] = (_Float16)f1[i];
                        hv[2] = (_Float16)f2[i];
                        hv[3] = (_Float16)f3[i];
                        *(f16x4*)((char*)smu.vst + (size_t)(d4 + i) * 80 + tb4 * 2) = hv;
                    }
                }
            }
            __syncthreads();
            f16x8 ap[4];
#pragma unroll
            for (int mt = 0; mt < 4; ++mt) {
                const int row = mt * 16 + lx;
                const int off = row * (BT * 2) + (((tc * 32 + g * 8) * 2) ^ ((row & 7) << 4));
                ap[mt] = *(const f16x8*)((const char*)pbuf + off);
            }
#pragma unroll
            for (int nt = 0; nt < 8; ++nt) {
                const int vrow = w * 128 + nt * 16 + lx;
                const char* vp = (const char*)smu.vst + (size_t)vrow * 80 + g * 16;
                union { f16x8 v8; f16x4 v4[2]; } bv;
                bv.v4[0] = *(const f16x4*)(vp);
                bv.v4[1] = *(const f16x4*)(vp + 8);
#pragma unroll
                for (int mt = 0; mt < 4; ++mt)
                    acc[mt][nt] = __builtin_amdgcn_mfma_f32_16x16x32_f16(ap[mt], bv.v8, acc[mt][nt], 0, 0, 0);
            }
        }
    }

    // ============ epilogue: O /= l, store ================================
    __syncthreads();
#pragma unroll
    for (int mt = 0; mt < 4; ++mt)
#pragma unroll
    for (int r = 0; r < 4; ++r) {
        const int row = mt * 16 + g * 4 + r;
        const float inv = 1.0f / l_s[row];
        float* orow = Out + ((size_t)(b * TQ + q0 + row)) * DH + w * 128 + lx;
#pragma unroll
        for (int nt = 0; nt < 8; ++nt)
            orow[nt * 16] = acc[mt][nt][r] * inv;
    }
}

extern "C" void kernel_launch(void* const* d_in, const int* in_sizes, int n_in,
                              void* d_out, int out_size, void* d_ws, size_t ws_size,
                              hipStream_t stream) {
    const float* q    = (const float*)d_in[0];
    const float* k    = (const float*)d_in[1];
    const float* v    = (const float*)d_in[2];
    const void*  mask = d_in[3];
    float* out = (float*)d_out;
    int* flag = (int*)d_ws;   // only 4 bytes of ws used

    hipLaunchKernelGGL(detect_mask_kernel, dim3(1), dim3(256), 0, stream, mask, flag);
    dim3 grid(TQ / BQ, B_);
    hipLaunchKernelGGL(flash_attn_kernel, grid, dim3(NTHR), 0, stream,
                       q, k, v, mask, flag, out);
}